// Round 13
// baseline (28.852 us; speedup 1.0000x reference)
//
#include <hip/hip_runtime.h>

// Separable RBF interpolation. w(m,n) = wy(my,n)*wx(mx,n);
// D[my][mx][ch] = sum_k wy*wx*Y[k][ch], Y[k][0]=1.
// Kernel 1: transpose y into d_ws as y_t[b][ch][k] (f16).
// Kernel 2: block = (batch, 32 my, 16 mx); 8 waves split K=2048 (256 each).
// WM=2 my-tiles per wave. Coords come from LDS (4 reads/step); y-fragments
// come from GLOBAL y_t via 16B broadcast loads (L1-resident) — LDS pipe
// only carries coords. Fixed-order 4-slot reduce, parallel normalize+store.

typedef float  f32x4 __attribute__((ext_vector_type(4)));
typedef __fp16 half8  __attribute__((ext_vector_type(8)));
typedef __fp16 half2t __attribute__((ext_vector_type(2)));

constexpr int B_  = 8;
constexpr int NC  = 2048;
constexpr int M_  = 128 * 128;
constexpr int BLK = 512;          // 8 waves
constexpr int KW  = 256;          // k-range per wave

// main-kernel LDS pool (bytes)
constexpr int OFF_SXT = 0;                         // 2048 f32 (s*x.x)
constexpr int OFF_SYT = OFF_SXT + NC * 4;          // 8192  (s*x.y)
constexpr int OFF_SG  = OFF_SYT + NC * 4;          // 16384 (48 floats)
// epilogue alias: 4 slots x [2][9][256] f32 = 73728 B
constexpr int SLOT_F  = 2 * 9 * 256;
constexpr int POOL_B  = 4 * SLOT_F * 4;            // 73728

// ---- kernel 1: y (B,NC,8) f32 -> y_t (B,8,NC) f16 ----
__global__ __launch_bounds__(256) void transpose_y(
    const float* __restrict__ y_c, __fp16* __restrict__ yt)
{
    __shared__ __fp16 ly[8][264];
    const int t  = (int)threadIdx.x;
    const int b  = blockIdx.x >> 3;
    const int k0 = (blockIdx.x & 7) * 256;

    const float4* yb = (const float4*)(y_c + ((size_t)b * NC + k0) * 8);
    const float4 a  = yb[2 * t];
    const float4 c4 = yb[2 * t + 1];
    ly[0][t] = (__fp16)a.x;  ly[1][t] = (__fp16)a.y;
    ly[2][t] = (__fp16)a.z;  ly[3][t] = (__fp16)a.w;
    ly[4][t] = (__fp16)c4.x; ly[5][t] = (__fp16)c4.y;
    ly[6][t] = (__fp16)c4.z; ly[7][t] = (__fp16)c4.w;
    __syncthreads();

    const int ch = t >> 5, kk = (t & 31) * 8;
    half8 v;
#pragma unroll
    for (int j = 0; j < 8; ++j) v[j] = ly[ch][kk + j];
    *(half8*)(yt + ((size_t)b * 8 + ch) * NC + k0 + kk) = v;
}

// ---- kernel 2: main ----
__global__ __launch_bounds__(BLK, 2) void rbf_sep(
    const float* __restrict__ x_c,
    const __fp16* __restrict__ yt,
    const float* __restrict__ gp,
    const float* __restrict__ sigma_p,
    float* __restrict__ out)
{
    __shared__ __align__(16) char pool[POOL_B];
    float* sxt = (float*)(pool + OFF_SXT);
    float* syt = (float*)(pool + OFF_SYT);
    float* sg  = (float*)(pool + OFF_SG);

    const int tid  = (int)threadIdx.x;
    const int lane = tid & 63;
    const int w    = tid >> 6;       // wave 0..7
    const int q    = lane >> 4;
    const int cl   = lane & 15;

    const int bid = blockIdx.x;
    const int b   = bid >> 5;                 // 32 blocks per batch
    const int myg = (bid >> 3) & 3;
    const int mxg = bid & 7;
    const int my0 = myg * 32;
    const int mx0 = mxg * 16;

    const float sigma = sigma_p[0];
    const float s = __builtin_sqrtf(0.72134752044448170f) / sigma;

    if (tid < 32)      sg[tid] = s * gp[(my0 + tid) * 256 + 1];
    else if (tid < 48) sg[tid] = s * gp[(mx0 + (tid - 32)) * 2];

    // stage coords (scaled SoA f32) for the full K range
    const float2* xb = (const float2*)x_c + (size_t)b * NC;
    for (int it = tid; it < NC; it += BLK) {
        const float2 v = xb[it];
        sxt[it] = s * v.x;
        syt[it] = s * v.y;
    }
    __syncthreads();

    const float sgy0 = sg[cl];         // my-tile 0: rows my0 + cl
    const float sgy1 = sg[16 + cl];    // my-tile 1: rows my0 + 16 + cl
    const float sgxr = sg[32 + cl];    // mx: cols mx0 + cl

    const __fp16* ytb = yt + (size_t)b * 8 * NC;

    f32x4 acc[2][9];
#pragma unroll
    for (int t = 0; t < 2; ++t)
#pragma unroll
        for (int c = 0; c < 9; ++c) acc[t][c] = (f32x4)0.0f;

    const int kbase = w * KW;
#pragma unroll 2
    for (int ks = 0; ks < KW / 32; ++ks) {
        const int kq = kbase + ks * 32 + q * 8;

        // y fragments from global (16B broadcast within q-group, L1-resident)
        half8 yf[8];
#pragma unroll
        for (int c = 0; c < 8; ++c)
            yf[c] = *(const half8*)(ytb + c * NC + kq);

        const f32x4 ya0 = *(const f32x4*)(syt + kq);
        const f32x4 ya1 = *(const f32x4*)(syt + kq + 4);
        const f32x4 xa0 = *(const f32x4*)(sxt + kq);
        const f32x4 xa1 = *(const f32x4*)(sxt + kq + 4);

        // A-fragment wy for my-tile 0
        const f32x4 y0e0 = ya0 - sgy0, y0e1 = ya1 - sgy0;
        const f32x4 y0m0 = y0e0 * y0e0, y0m1 = y0e1 * y0e1;
        const half2t p00 = __builtin_amdgcn_cvt_pkrtz(
            __builtin_amdgcn_exp2f(-y0m0.x), __builtin_amdgcn_exp2f(-y0m0.y));
        const half2t p01 = __builtin_amdgcn_cvt_pkrtz(
            __builtin_amdgcn_exp2f(-y0m0.z), __builtin_amdgcn_exp2f(-y0m0.w));
        const half2t p02 = __builtin_amdgcn_cvt_pkrtz(
            __builtin_amdgcn_exp2f(-y0m1.x), __builtin_amdgcn_exp2f(-y0m1.y));
        const half2t p03 = __builtin_amdgcn_cvt_pkrtz(
            __builtin_amdgcn_exp2f(-y0m1.z), __builtin_amdgcn_exp2f(-y0m1.w));
        const half8 af0 = (half8){p00.x, p00.y, p01.x, p01.y, p02.x, p02.y, p03.x, p03.y};

        // A-fragment wy for my-tile 1
        const f32x4 y1e0 = ya0 - sgy1, y1e1 = ya1 - sgy1;
        const f32x4 y1m0 = y1e0 * y1e0, y1m1 = y1e1 * y1e1;
        const half2t p10 = __builtin_amdgcn_cvt_pkrtz(
            __builtin_amdgcn_exp2f(-y1m0.x), __builtin_amdgcn_exp2f(-y1m0.y));
        const half2t p11 = __builtin_amdgcn_cvt_pkrtz(
            __builtin_amdgcn_exp2f(-y1m0.z), __builtin_amdgcn_exp2f(-y1m0.w));
        const half2t p12 = __builtin_amdgcn_cvt_pkrtz(
            __builtin_amdgcn_exp2f(-y1m1.x), __builtin_amdgcn_exp2f(-y1m1.y));
        const half2t p13 = __builtin_amdgcn_cvt_pkrtz(
            __builtin_amdgcn_exp2f(-y1m1.z), __builtin_amdgcn_exp2f(-y1m1.w));
        const half8 af1 = (half8){p10.x, p10.y, p11.x, p11.y, p12.x, p12.y, p13.x, p13.y};

        // B-fragment wx (shared across both my-tiles)
        const f32x4 xe0 = xa0 - sgxr, xe1 = xa1 - sgxr;
        const f32x4 xm0 = xe0 * xe0,   xm1 = xe1 * xe1;
        const half2t b0 = __builtin_amdgcn_cvt_pkrtz(
            __builtin_amdgcn_exp2f(-xm0.x), __builtin_amdgcn_exp2f(-xm0.y));
        const half2t b1 = __builtin_amdgcn_cvt_pkrtz(
            __builtin_amdgcn_exp2f(-xm0.z), __builtin_amdgcn_exp2f(-xm0.w));
        const half2t b2 = __builtin_amdgcn_cvt_pkrtz(
            __builtin_amdgcn_exp2f(-xm1.x), __builtin_amdgcn_exp2f(-xm1.y));
        const half2t b3 = __builtin_amdgcn_cvt_pkrtz(
            __builtin_amdgcn_exp2f(-xm1.z), __builtin_amdgcn_exp2f(-xm1.w));
        const half8 bx = (half8){b0.x, b0.y, b1.x, b1.y, b2.x, b2.y, b3.x, b3.y};

        acc[0][0] = __builtin_amdgcn_mfma_f32_16x16x32_f16(af0, bx, acc[0][0], 0, 0, 0);
        acc[1][0] = __builtin_amdgcn_mfma_f32_16x16x32_f16(af1, bx, acc[1][0], 0, 0, 0);
#pragma unroll
        for (int c = 0; c < 8; ++c) {
            const half8 bxy = bx * yf[c];   // shared for both tiles
            acc[0][c + 1] = __builtin_amdgcn_mfma_f32_16x16x32_f16(af0, bxy, acc[0][c + 1], 0, 0, 0);
            acc[1][c + 1] = __builtin_amdgcn_mfma_f32_16x16x32_f16(af1, bxy, acc[1][c + 1], 0, 0, 0);
        }
    }

    // ---- flat reduce: slot_s = acc_{s+4} + acc_s; final = (s0+s1)+(s2+s3) ----
    __syncthreads();                       // coords dead; alias slot bufs
    float* slots = (float*)pool;           // [4][2][9][256]
    if (w >= 4) {
        float* rb = slots + (w - 4) * SLOT_F;
#pragma unroll
        for (int t = 0; t < 2; ++t)
#pragma unroll
            for (int c = 0; c < 9; ++c)
#pragma unroll
                for (int r = 0; r < 4; ++r)
                    rb[t * 2304 + c * 256 + (q * 4 + r) * 16 + cl] = acc[t][c][r];
    }
    __syncthreads();
    if (w < 4) {
        float* rb = slots + w * SLOT_F;
#pragma unroll
        for (int t = 0; t < 2; ++t)
#pragma unroll
            for (int c = 0; c < 9; ++c)
#pragma unroll
                for (int r = 0; r < 4; ++r) {
                    const int idx = t * 2304 + c * 256 + (q * 4 + r) * 16 + cl;
                    rb[idx] = rb[idx] + acc[t][c][r];   // acc_{w+4} + acc_w
                }
    }
    __syncthreads();

    // final 4-way sum + normalize + store: thread -> (t, my, mx), 512 total
    {
        float* ob = out + (size_t)b * 9 * M_;
        const int t  = tid >> 8;
        const int my = (tid >> 4) & 15;
        const int mx = tid & 15;
        const size_t mo = (size_t)(my0 + t * 16 + my) * 128 + mx0 + mx;
        float v[9];
#pragma unroll
        for (int c = 0; c < 9; ++c) {
            const int idx = t * 2304 + c * 256 + my * 16 + mx;
            v[c] = (slots[idx] + slots[SLOT_F + idx]) +
                   (slots[2 * SLOT_F + idx] + slots[3 * SLOT_F + idx]);
        }
        const float inv = __builtin_amdgcn_rcpf(v[0] + 1e-5f);
        ob[mo] = v[0];
#pragma unroll
        for (int c = 1; c < 9; ++c)
            ob[(size_t)c * M_ + mo] = v[c] * inv;
    }
}

extern "C" void kernel_launch(void* const* d_in, const int* in_sizes, int n_in,
                              void* d_out, int out_size, void* d_ws, size_t ws_size,
                              hipStream_t stream) {
    const float* x_c   = (const float*)d_in[0];
    const float* y_c   = (const float*)d_in[1];
    const float* gp    = (const float*)d_in[2];
    const float* sigma = (const float*)d_in[3];
    float* out  = (float*)d_out;
    __fp16* yt  = (__fp16*)d_ws;   // 8*8*2048 f16 = 262144 B

    transpose_y<<<dim3(B_ * 8), dim3(256), 0, stream>>>(y_c, yt);

    dim3 grid(B_ * 32);      // 256 blocks: 8 batches x 4 my-groups x 8 mx-groups
    rbf_sep<<<grid, dim3(BLK), 0, stream>>>(x_c, yt, gp, sigma, out);
}

// Round 14
// 15.629 us; speedup vs baseline: 1.8461x; 1.8461x over previous
//
#include <hip/hip_runtime.h>

// Separable RBF interpolation. w(m,n)=wy(my,n)*wx(mx,n);
// D[my][mx][ch] = sum_k wy*wx*Y[k][ch], Y[k][0]=1.
// Block = (batch, 32 my, 16 mx); 8 waves split K=2048 (256 each), WM=2.
// Inner loop is software-pipelined 2 deep: step k+1's LDS reads issue before
// step k's compute (hides LDS latency at 2 waves/SIMD).
// Reduce dumps acc via ds_write_b128 ([t][c][lane][4] layout), fixed order.

typedef float  f32x4 __attribute__((ext_vector_type(4)));
typedef __fp16 half8  __attribute__((ext_vector_type(8)));
typedef __fp16 half2t __attribute__((ext_vector_type(2)));

constexpr int B_  = 8;
constexpr int NC  = 2048;
constexpr int M_  = 128 * 128;
constexpr int BLK = 512;          // 8 waves
constexpr int KW  = 256;          // k-range per wave
constexpr int LDHY = NC + 8;      // padded f16 row stride for y (2056)

// LDS pool carve (bytes)
constexpr int OFF_SXT = 0;                         // 2048 f32 (s*x.x)
constexpr int OFF_SYT = OFF_SXT + NC * 4;          // 8192  (s*x.y)
constexpr int OFF_SYS = OFF_SYT + NC * 4;          // 16384 y f16 [8][LDHY]
constexpr int OFF_SG  = OFF_SYS + 8 * LDHY * 2;    // 49280 (48 floats)
// epilogue alias: 4 slots x [2][9][64][4] f32
constexpr int SLOT_F  = 2 * 9 * 64 * 4;            // 4608 floats / slot
constexpr int POOL_B  = 4 * SLOT_F * 4;            // 73728 B

__global__ __launch_bounds__(BLK, 2) void rbf_sep(
    const float* __restrict__ x_c,
    const float* __restrict__ y_c,
    const float* __restrict__ gp,
    const float* __restrict__ sigma_p,
    float* __restrict__ out)
{
    __shared__ __align__(16) char pool[POOL_B];
    float*  sxt = (float*)(pool + OFF_SXT);
    float*  syt = (float*)(pool + OFF_SYT);
    __fp16* sys = (__fp16*)(pool + OFF_SYS);
    float*  sg  = (float*)(pool + OFF_SG);

    const int tid  = (int)threadIdx.x;
    const int lane = tid & 63;
    const int w    = tid >> 6;       // wave 0..7
    const int q    = lane >> 4;
    const int cl   = lane & 15;

    const int bid = blockIdx.x;
    const int b   = bid >> 5;                 // 32 blocks per batch
    const int myg = (bid >> 3) & 3;
    const int mxg = bid & 7;
    const int my0 = myg * 32;
    const int mx0 = mxg * 16;

    const float sigma = sigma_p[0];
    const float s = __builtin_sqrtf(0.72134752044448170f) / sigma;

    if (tid < 32)      sg[tid] = s * gp[(my0 + tid) * 256 + 1];
    else if (tid < 48) sg[tid] = s * gp[(mx0 + (tid - 32)) * 2];

    // stage x (scaled SoA f32) and y (f16 [ch][k]) for the full K range
    const float2* xb = (const float2*)x_c + (size_t)b * NC;
    const float4* yb = (const float4*)y_c + (size_t)b * NC * 2;
    for (int it = tid; it < NC; it += BLK) {
        const float2 v = xb[it];
        sxt[it] = s * v.x;
        syt[it] = s * v.y;
        const float4 y0 = yb[(size_t)it * 2];
        const float4 y1 = yb[(size_t)it * 2 + 1];
        __fp16* yw = sys + it;
        yw[0 * LDHY] = (__fp16)y0.x;
        yw[1 * LDHY] = (__fp16)y0.y;
        yw[2 * LDHY] = (__fp16)y0.z;
        yw[3 * LDHY] = (__fp16)y0.w;
        yw[4 * LDHY] = (__fp16)y1.x;
        yw[5 * LDHY] = (__fp16)y1.y;
        yw[6 * LDHY] = (__fp16)y1.z;
        yw[7 * LDHY] = (__fp16)y1.w;
    }
    __syncthreads();

    const float sgy0 = sg[cl];         // my-tile 0: rows my0 + cl
    const float sgy1 = sg[16 + cl];    // my-tile 1: rows my0 + 16 + cl
    const float sgxr = sg[32 + cl];    // mx: cols mx0 + cl

    f32x4 acc[2][9];
#pragma unroll
    for (int t = 0; t < 2; ++t)
#pragma unroll
        for (int c = 0; c < 9; ++c) acc[t][c] = (f32x4)0.0f;

    const int kbase = w * KW + q * 8;

    // two register staging sets (A/B) for the 2-deep pipeline
    f32x4 Aya0, Aya1, Axa0, Axa1; half8 Ayf[8];
    f32x4 Bya0, Bya1, Bxa0, Bxa1; half8 Byf[8];

#define LOADSTEP(ks, Y0, Y1, X0, X1, YF)                         \
    {                                                            \
        const int kq = kbase + (ks) * 32;                        \
        Y0 = *(const f32x4*)(syt + kq);                          \
        Y1 = *(const f32x4*)(syt + kq + 4);                      \
        X0 = *(const f32x4*)(sxt + kq);                          \
        X1 = *(const f32x4*)(sxt + kq + 4);                      \
        _Pragma("unroll")                                        \
        for (int c = 0; c < 8; ++c)                              \
            YF[c] = *(const half8*)(sys + c * LDHY + kq);        \
    }

#define COMPUTE(Y0, Y1, X0, X1, YF)                                               \
    {                                                                             \
        const f32x4 y0e0 = Y0 - sgy0, y0e1 = Y1 - sgy0;                           \
        const f32x4 y0m0 = y0e0 * y0e0, y0m1 = y0e1 * y0e1;                       \
        const half2t p00 = __builtin_amdgcn_cvt_pkrtz(                            \
            __builtin_amdgcn_exp2f(-y0m0.x), __builtin_amdgcn_exp2f(-y0m0.y));    \
        const half2t p01 = __builtin_amdgcn_cvt_pkrtz(                            \
            __builtin_amdgcn_exp2f(-y0m0.z), __builtin_amdgcn_exp2f(-y0m0.w));    \
        const half2t p02 = __builtin_amdgcn_cvt_pkrtz(                            \
            __builtin_amdgcn_exp2f(-y0m1.x), __builtin_amdgcn_exp2f(-y0m1.y));    \
        const half2t p03 = __builtin_amdgcn_cvt_pkrtz(                            \
            __builtin_amdgcn_exp2f(-y0m1.z), __builtin_amdgcn_exp2f(-y0m1.w));    \
        const half8 af0 = (half8){p00.x, p00.y, p01.x, p01.y,                     \
                                  p02.x, p02.y, p03.x, p03.y};                    \
        const f32x4 y1e0 = Y0 - sgy1, y1e1 = Y1 - sgy1;                           \
        const f32x4 y1m0 = y1e0 * y1e0, y1m1 = y1e1 * y1e1;                       \
        const half2t p10 = __builtin_amdgcn_cvt_pkrtz(                            \
            __builtin_amdgcn_exp2f(-y1m0.x), __builtin_amdgcn_exp2f(-y1m0.y));    \
        const half2t p11 = __builtin_amdgcn_cvt_pkrtz(                            \
            __builtin_amdgcn_exp2f(-y1m0.z), __builtin_amdgcn_exp2f(-y1m0.w));    \
        const half2t p12 = __builtin_amdgcn_cvt_pkrtz(                            \
            __builtin_amdgcn_exp2f(-y1m1.x), __builtin_amdgcn_exp2f(-y1m1.y));    \
        const half2t p13 = __builtin_amdgcn_cvt_pkrtz(                            \
            __builtin_amdgcn_exp2f(-y1m1.z), __builtin_amdgcn_exp2f(-y1m1.w));    \
        const half8 af1 = (half8){p10.x, p10.y, p11.x, p11.y,                     \
                                  p12.x, p12.y, p13.x, p13.y};                    \
        const f32x4 xe0 = X0 - sgxr, xe1 = X1 - sgxr;                             \
        const f32x4 xm0 = xe0 * xe0,  xm1 = xe1 * xe1;                            \
        const half2t b0 = __builtin_amdgcn_cvt_pkrtz(                             \
            __builtin_amdgcn_exp2f(-xm0.x), __builtin_amdgcn_exp2f(-xm0.y));      \
        const half2t b1 = __builtin_amdgcn_cvt_pkrtz(                             \
            __builtin_amdgcn_exp2f(-xm0.z), __builtin_amdgcn_exp2f(-xm0.w));      \
        const half2t b2 = __builtin_amdgcn_cvt_pkrtz(                             \
            __builtin_amdgcn_exp2f(-xm1.x), __builtin_amdgcn_exp2f(-xm1.y));      \
        const half2t b3 = __builtin_amdgcn_cvt_pkrtz(                             \
            __builtin_amdgcn_exp2f(-xm1.z), __builtin_amdgcn_exp2f(-xm1.w));      \
        const half8 bx = (half8){b0.x, b0.y, b1.x, b1.y, b2.x, b2.y, b3.x, b3.y}; \
        acc[0][0] = __builtin_amdgcn_mfma_f32_16x16x32_f16(af0, bx, acc[0][0], 0, 0, 0); \
        acc[1][0] = __builtin_amdgcn_mfma_f32_16x16x32_f16(af1, bx, acc[1][0], 0, 0, 0); \
        _Pragma("unroll")                                                         \
        for (int c = 0; c < 8; ++c) {                                             \
            const half8 bxy = bx * YF[c];                                         \
            acc[0][c + 1] = __builtin_amdgcn_mfma_f32_16x16x32_f16(af0, bxy, acc[0][c + 1], 0, 0, 0); \
            acc[1][c + 1] = __builtin_amdgcn_mfma_f32_16x16x32_f16(af1, bxy, acc[1][c + 1], 0, 0, 0); \
        }                                                                         \
    }

    LOADSTEP(0, Aya0, Aya1, Axa0, Axa1, Ayf)
#pragma unroll
    for (int ks = 0; ks < 8; ks += 2) {
        LOADSTEP(ks + 1, Bya0, Bya1, Bxa0, Bxa1, Byf)
        COMPUTE(Aya0, Aya1, Axa0, Axa1, Ayf)
        if (ks + 2 < 8) {
            LOADSTEP(ks + 2, Aya0, Aya1, Axa0, Axa1, Ayf)
        }
        COMPUTE(Bya0, Bya1, Bxa0, Bxa1, Byf)
    }
#undef LOADSTEP
#undef COMPUTE

    // ---- flat reduce (b128 dumps): slot_s = acc_{s+4} + acc_s ----
    __syncthreads();                       // tiles dead; alias slot bufs
    float* slots = (float*)pool;           // [4][2][9][64][4]
    if (w >= 4) {
        float* rb = slots + (w - 4) * SLOT_F;
#pragma unroll
        for (int t = 0; t < 2; ++t)
#pragma unroll
            for (int c = 0; c < 9; ++c)
                *(f32x4*)(rb + ((t * 9 + c) * 64 + lane) * 4) = acc[t][c];
    }
    __syncthreads();
    if (w < 4) {
        float* rb = slots + w * SLOT_F;
#pragma unroll
        for (int t = 0; t < 2; ++t)
#pragma unroll
            for (int c = 0; c < 9; ++c) {
                float* p = rb + ((t * 9 + c) * 64 + lane) * 4;
                *(f32x4*)p = *(const f32x4*)p + acc[t][c];   // acc_{w+4} + acc_w
            }
    }
    __syncthreads();

    // final 4-way sum + normalize + store: thread -> (t, my, mx), 512 total
    {
        float* ob = out + (size_t)b * 9 * M_;
        const int t  = tid >> 8;
        const int my = (tid >> 4) & 15;
        const int mx = tid & 15;
        const size_t mo = (size_t)(my0 + t * 16 + my) * 128 + mx0 + mx;
        // acc element r of lane (q,cl) = row q*4+r, col cl -> lane=(my>>2)*16+mx, r=my&3
        const int eidx = ((my >> 2) * 16 + mx) * 4 + (my & 3);
        float v[9];
#pragma unroll
        for (int c = 0; c < 9; ++c) {
            const int idx = (t * 9 + c) * 256 + eidx;
            v[c] = (slots[idx] + slots[SLOT_F + idx]) +
                   (slots[2 * SLOT_F + idx] + slots[3 * SLOT_F + idx]);
        }
        const float inv = __builtin_amdgcn_rcpf(v[0] + 1e-5f);
        ob[mo] = v[0];
#pragma unroll
        for (int c = 1; c < 9; ++c)
            ob[(size_t)c * M_ + mo] = v[c] * inv;
    }
}

extern "C" void kernel_launch(void* const* d_in, const int* in_sizes, int n_in,
                              void* d_out, int out_size, void* d_ws, size_t ws_size,
                              hipStream_t stream) {
    const float* x_c   = (const float*)d_in[0];
    const float* y_c   = (const float*)d_in[1];
    const float* gp    = (const float*)d_in[2];
    const float* sigma = (const float*)d_in[3];
    float* out = (float*)d_out;

    dim3 grid(B_ * 32);      // 256 blocks: 8 batches x 4 my-groups x 8 mx-groups
    dim3 block(BLK);
    rbf_sep<<<grid, block, 0, stream>>>(x_c, y_c, gp, sigma, out);
}